// Round 9
// baseline (326.538 us; speedup 1.0000x reference)
//
#include <hip/hip_runtime.h>

#define N_NODES 100000
#define N_EDGES 1600000
#define NBKT 196          // ceil(100000 / 512)
#define BKT_SHIFT 9
#define BKT_MASK 511

typedef __attribute__((ext_vector_type(8))) short short8;
typedef __attribute__((ext_vector_type(4))) float float4v;

__device__ __forceinline__ unsigned short f2bf(float f) {  // RNE
  unsigned u = __float_as_uint(f);
  return (unsigned short)((u + 0x7fffu + ((u >> 16) & 1u)) >> 16);
}
__device__ __forceinline__ float bflo(unsigned d) { return __uint_as_float(d << 16); }
__device__ __forceinline__ float bfhi(unsigned d) { return __uint_as_float(d & 0xffff0000u); }

// ---- binning: edges grouped by 512-node dst bucket -------------------------

__global__ void kA_count(const int* __restrict__ dst, int* __restrict__ blkCnt) {
  __shared__ int hist[NBKT];
  for (int t = threadIdx.x; t < NBKT; t += 256) hist[t] = 0;
  __syncthreads();
  const int chunk = (N_EDGES + gridDim.x - 1) / gridDim.x;
  const int e0 = blockIdx.x * chunk;
  const int e1 = min(e0 + chunk, N_EDGES);
  for (int e = e0 + threadIdx.x; e < e1; e += 256)
    atomicAdd(&hist[dst[e] >> BKT_SHIFT], 1);
  __syncthreads();
  for (int t = threadIdx.x; t < NBKT; t += 256)
    blkCnt[t * 256 + blockIdx.x] = hist[t];
}

__global__ void kA_scan1(int* __restrict__ blkCnt, int* __restrict__ bktTot) {
  const int b = blockIdx.x;
  const int tid = threadIdx.x, lane = tid & 63, w = tid >> 6;
  int v = blkCnt[b * 256 + tid];
  int inc = v;
  #pragma unroll
  for (int d = 1; d < 64; d <<= 1) { int y = __shfl_up(inc, d); if (lane >= d) inc += y; }
  __shared__ int wtot[4];
  if (lane == 63) wtot[w] = inc;
  __syncthreads();
  int base = 0;
  for (int j = 0; j < w; j++) base += wtot[j];
  blkCnt[b * 256 + tid] = base + inc - v;
  if (tid == 255) bktTot[b] = base + inc;
}

__global__ void kA_scan2(const int* __restrict__ bktTot, int* __restrict__ bktStart) {
  int lane = threadIdx.x;
  int running = 0;
  for (int base = 0; base < NBKT; base += 64) {
    int i = base + lane;
    int v = (i < NBKT) ? bktTot[i] : 0;
    int inc = v;
    #pragma unroll
    for (int d = 1; d < 64; d <<= 1) { int y = __shfl_up(inc, d); if (lane >= d) inc += y; }
    if (i < NBKT) bktStart[i] = running + inc - v;
    running += __shfl(inc, 63);
  }
}

__global__ void kA_scatter(const int* __restrict__ src, const int* __restrict__ dst,
                           const int* __restrict__ blkCnt, const int* __restrict__ bktStart,
                           int* __restrict__ binned) {
  __shared__ int curb[NBKT];
  for (int t = threadIdx.x; t < NBKT; t += 256)
    curb[t] = bktStart[t] + blkCnt[t * 256 + blockIdx.x];
  __syncthreads();
  const int chunk = (N_EDGES + gridDim.x - 1) / gridDim.x;
  const int e0 = blockIdx.x * chunk;
  const int e1 = min(e0 + chunk, N_EDGES);
  for (int e = e0 + threadIdx.x; e < e1; e += 256) {
    int d = dst[e];
    int s = src[e];
    int b = d >> BKT_SHIFT;
    int p = atomicAdd(&curb[b], 1);
    binned[p] = s | ((d & BKT_MASK) << 17);   // src:17 bits | dlocal:9 bits
  }
}

// ---- merged counting sort (512 threads): hist + scan -> off, place -> esrc -

__global__ __launch_bounds__(512)
void k_sort(const int* __restrict__ binned, const int* __restrict__ bktStart,
            const int* __restrict__ bktTot,
            int* __restrict__ off, int* __restrict__ esrc) {
  const int b = blockIdx.x;
  const int tid = threadIdx.x, lane = tid & 63, w = tid >> 6;  // 8 waves
  __shared__ int cnt[512];
  __shared__ int pos[512];
  cnt[tid] = 0;
  __syncthreads();
  const int s0 = bktStart[b], ne = bktTot[b];
  for (int i = tid; i < ne; i += 512)
    atomicAdd(&cnt[binned[s0 + i] >> 17], 1);
  __syncthreads();
  int v = cnt[tid];
  int inc = v;
  #pragma unroll
  for (int d = 1; d < 64; d <<= 1) { int y = __shfl_up(inc, d); if (lane >= d) inc += y; }
  __shared__ int wtot[8];
  if (lane == 63) wtot[w] = inc;
  __syncthreads();
  int base = s0;
  for (int j = 0; j < w; j++) base += wtot[j];
  int ex = base + inc - v;   // global edge offset of node (b<<9)+tid
  pos[tid] = ex;
  int n0 = (b << BKT_SHIFT) + tid;
  if (n0 < N_NODES) off[n0] = ex;
  if (b == NBKT - 1 && tid == 0) off[N_NODES] = N_EDGES;
  __syncthreads();
  for (int i = tid; i < ne; i += 512) {
    int pe = binned[s0 + i];
    int p = atomicAdd(&pos[pe >> 17], 1);
    esrc[p] = pe & 0x1FFFF;
  }
}

// ---- merged prep: f32->bf16 table cvt + weight frag swizzle ----------------

__global__ void k_prep(const float* __restrict__ in, unsigned short* __restrict__ outb,
                       const float* __restrict__ W0, const float* __restrict__ W1,
                       const float* __restrict__ W2, const float* __restrict__ W3,
                       unsigned short* __restrict__ F) {
  const int NC = (N_NODES * 16 + 255) / 256;  // 6250 cvt blocks
  if (blockIdx.x < NC) {
    int i = blockIdx.x * 256 + threadIdx.x;
    const int n4 = (N_NODES * 64) / 4;
    if (i < n4) {
      float4 v = ((const float4*)in)[i];
      unsigned d0 = ((unsigned)f2bf(v.y) << 16) | f2bf(v.x);
      unsigned d1 = ((unsigned)f2bf(v.w) << 16) | f2bf(v.z);
      ((uint2*)outb)[i] = make_uint2(d0, d1);
    }
    return;
  }
  if (threadIdx.x >= 64) return;
  const int q = blockIdx.x - NC;  // 0..3
  const float* W = (q == 0) ? W0 : (q == 1) ? W1 : (q == 2) ? W2 : W3;
  unsigned short* out = F + q * 4096;
  int lane = threadIdx.x;
  int col = lane & 15, kr = lane >> 4;
  #pragma unroll
  for (int kc = 0; kc < 2; kc++)
    #pragma unroll
    for (int nt = 0; nt < 4; nt++) {
      unsigned d[4];
      #pragma unroll
      for (int jj = 0; jj < 4; jj++) {
        float w0 = W[(kc * 32 + kr * 8 + 2 * jj)     * 64 + nt * 16 + col];
        float w1 = W[(kc * 32 + kr * 8 + 2 * jj + 1) * 64 + nt * 16 + col];
        d[jj] = ((unsigned)f2bf(w1) << 16) | f2bf(w0);
      }
      uint4* p = (uint4*)(out + ((kc * 4 + nt) * 64 + lane) * 8);
      *p = make_uint4(d[0], d[1], d[2], d[3]);
    }
}

// ---- fused layer: gather-aggregate (R8-proven loop) + MFMA transform -------
// wave = one 16-node tile. Agg rows land in a wave-private LDS tile in
// A-fragment order (skew slot (m+2c)&15: writer 2-way conflict = free,
// reader phases conflict-free), then 16 MFMAs. B-frags staged in LDS.

template <bool RELU, bool OUT_BF>
__global__ __launch_bounds__(256)
void k_layerf(const unsigned short* __restrict__ featb,
              const int* __restrict__ off, const int* __restrict__ esrc,
              const unsigned short* __restrict__ wfS,
              const unsigned short* __restrict__ wfN,
              const float* __restrict__ bias,
              float* __restrict__ outf, unsigned short* __restrict__ outb) {
  __shared__ unsigned short wlds[8192];      // 16 KB: S-frags [0,4096), N-frags [4096,8192)
  __shared__ unsigned short atile[4][1024];  // 2 KB agg tile per wave

  const int tid = threadIdx.x;
  {
    const uint4* gs = (const uint4*)wfS;
    const uint4* gn = (const uint4*)wfN;
    uint4* l = (uint4*)wlds;
    for (int i = tid; i < 512; i += 256) { l[i] = gs[i]; l[512 + i] = gn[i]; }
  }
  __syncthreads();

  const int lane = tid & 63;
  const int wib  = tid >> 6;
  const int r = lane >> 3, c = lane & 7;      // gather layout
  const int col = lane & 15, rr = lane >> 4;  // MFMA layout
  const int wid = (blockIdx.x << 2) | wib;
  const int nw  = gridDim.x << 2;

  float bv[4];
  #pragma unroll
  for (int nt = 0; nt < 4; nt++) bv[nt] = bias[nt * 16 + col];

  unsigned short* at = atile[wib];
  const int NT = N_NODES / 16;  // 6250

  for (int t = wid; t < NT; t += nw) {
    // ---- phase 1: aggregate 16 nodes into the LDS tile ----
    for (int m = 0; m < 16; m++) {
      const int n = t * 16 + m;
      const int o0 = off[n], o1 = off[n + 1];
      float acc[8];
      #pragma unroll
      for (int j = 0; j < 8; j++) acc[j] = 0.f;

      int i = o0;
      for (; i + 16 <= o1; i += 16) {
        int sA = esrc[i + r];
        int sB = esrc[i + 8 + r];
        uint4 vA = *(const uint4*)(featb + sA * 64 + c * 8);
        uint4 vB = *(const uint4*)(featb + sB * 64 + c * 8);
        acc[0] += bflo(vA.x); acc[1] += bfhi(vA.x);
        acc[2] += bflo(vA.y); acc[3] += bfhi(vA.y);
        acc[4] += bflo(vA.z); acc[5] += bfhi(vA.z);
        acc[6] += bflo(vA.w); acc[7] += bfhi(vA.w);
        acc[0] += bflo(vB.x); acc[1] += bfhi(vB.x);
        acc[2] += bflo(vB.y); acc[3] += bfhi(vB.y);
        acc[4] += bflo(vB.z); acc[5] += bfhi(vB.z);
        acc[6] += bflo(vB.w); acc[7] += bfhi(vB.w);
      }
      if (i + 8 <= o1) {
        int s = esrc[i + r];
        uint4 v = *(const uint4*)(featb + s * 64 + c * 8);
        acc[0] += bflo(v.x); acc[1] += bfhi(v.x);
        acc[2] += bflo(v.y); acc[3] += bfhi(v.y);
        acc[4] += bflo(v.z); acc[5] += bfhi(v.z);
        acc[6] += bflo(v.w); acc[7] += bfhi(v.w);
        i += 8;
      }
      if (i < o1) {
        int e = i + r;
        if (e < o1) {
          int s = esrc[e];
          uint4 v = *(const uint4*)(featb + s * 64 + c * 8);
          acc[0] += bflo(v.x); acc[1] += bfhi(v.x);
          acc[2] += bflo(v.y); acc[3] += bfhi(v.y);
          acc[4] += bflo(v.z); acc[5] += bfhi(v.z);
          acc[6] += bflo(v.w); acc[7] += bfhi(v.w);
        }
      }
      #pragma unroll
      for (int mm = 8; mm <= 32; mm <<= 1)
        #pragma unroll
        for (int j = 0; j < 8; j++) acc[j] += __shfl_xor(acc[j], mm);

      const int dg = o1 - o0;
      const float inv = (dg > 0) ? (1.0f / (float)dg) : 0.f;
      if (r == 0) {
        unsigned d0 = ((unsigned)f2bf(acc[1] * inv) << 16) | f2bf(acc[0] * inv);
        unsigned d1 = ((unsigned)f2bf(acc[3] * inv) << 16) | f2bf(acc[2] * inv);
        unsigned d2 = ((unsigned)f2bf(acc[5] * inv) << 16) | f2bf(acc[4] * inv);
        unsigned d3 = ((unsigned)f2bf(acc[7] * inv) << 16) | f2bf(acc[6] * inv);
        // octet c of node m -> frag (c>>2), region (c&3), skewed slot (m+2c)&15
        uint4* p = (uint4*)(at + (c >> 2) * 512 + (c & 3) * 128 + (((m + 2 * c) & 15) * 8));
        *p = make_uint4(d0, d1, d2, d3);
      }
    }
    // same-wave LDS write->read: compiler inserts lgkmcnt waits; no barrier

    // ---- phase 2: MFMA transform of this tile ----
    const int mrow = t * 16 + col;
    short8 as0 = *(const short8*)(featb + mrow * 64 + rr * 8);
    short8 as1 = *(const short8*)(featb + mrow * 64 + 32 + rr * 8);
    short8 aa0 = *(const short8*)(at + rr * 128 + (((col + 2 * rr) & 15) * 8));
    short8 aa1 = *(const short8*)(at + 512 + rr * 128 + (((col + 2 * rr + 8) & 15) * 8));
    #pragma unroll
    for (int nt = 0; nt < 4; nt++) {
      short8 b0 = *(const short8*)(wlds + ((0 * 4 + nt) * 64 + lane) * 8);
      short8 b1 = *(const short8*)(wlds + ((1 * 4 + nt) * 64 + lane) * 8);
      short8 c0 = *(const short8*)(wlds + 4096 + ((0 * 4 + nt) * 64 + lane) * 8);
      short8 c1 = *(const short8*)(wlds + 4096 + ((1 * 4 + nt) * 64 + lane) * 8);
      float4v cfr = {bv[nt], bv[nt], bv[nt], bv[nt]};
      cfr = __builtin_amdgcn_mfma_f32_16x16x32_bf16(as0, b0, cfr, 0, 0, 0);
      cfr = __builtin_amdgcn_mfma_f32_16x16x32_bf16(as1, b1, cfr, 0, 0, 0);
      cfr = __builtin_amdgcn_mfma_f32_16x16x32_bf16(aa0, c0, cfr, 0, 0, 0);
      cfr = __builtin_amdgcn_mfma_f32_16x16x32_bf16(aa1, c1, cfr, 0, 0, 0);
      #pragma unroll
      for (int r2 = 0; r2 < 4; r2++) {
        int row = t * 16 + rr * 4 + r2;  // C/D: row=(lane>>4)*4+reg, col=lane&15
        float v = cfr[r2];
        if (RELU) v = fmaxf(v, 0.f);
        if (OUT_BF) outb[row * 64 + nt * 16 + col] = f2bf(v);
        else        outf[row * 64 + nt * 16 + col] = v;
      }
    }
  }
}

// ---- launch ----------------------------------------------------------------

extern "C" void kernel_launch(void* const* d_in, const int* in_sizes, int n_in,
                              void* d_out, int out_size, void* d_ws, size_t ws_size,
                              hipStream_t stream) {
  const float* x   = (const float*)d_in[0];
  const int*   src = (const int*)d_in[1];
  const int*   dst = (const int*)d_in[2];
  const float* Ws1 = (const float*)d_in[3];
  const float* Wn1 = (const float*)d_in[4];
  const float* b1  = (const float*)d_in[5];
  const float* Ws2 = (const float*)d_in[6];
  const float* Wn2 = (const float*)d_in[7];
  const float* b2  = (const float*)d_in[8];

  char* ws = (char*)d_ws;
  int*            blkCnt   = (int*)(ws + 0);          // NBKT*256 ints
  int*            bktTot   = (int*)(ws + 262144);     // NBKT ints
  int*            bktStart = (int*)(ws + 266240);     // NBKT ints
  unsigned short* wf       = (unsigned short*)(ws + 270336);   // 32 KB
  int*            binned   = (int*)(ws + 303104);     // E ints (6.4 MB)
  int*            off      = (int*)(ws + 6703104);    // N+1 ints
  int*            esrc     = (int*)(ws + 7103488);    // E ints (6.4 MB)
  unsigned short* xbf      = (unsigned short*)(ws + 13503488);  // N*64 bf16
  unsigned short* hbf      = (unsigned short*)(ws + 26303488);  // N*64 bf16

  kA_count<<<256, 256, 0, stream>>>(dst, blkCnt);
  kA_scan1<<<NBKT, 256, 0, stream>>>(blkCnt, bktTot);
  kA_scan2<<<1, 64, 0, stream>>>(bktTot, bktStart);
  kA_scatter<<<256, 256, 0, stream>>>(src, dst, blkCnt, bktStart, binned);
  k_sort<<<NBKT, 512, 0, stream>>>(binned, bktStart, bktTot, off, esrc);

  k_prep<<<6254, 256, 0, stream>>>(x, xbf, Ws1, Wn1, Ws2, Wn2, wf);

  k_layerf<true,  true ><<<1563, 256, 0, stream>>>(xbf, off, esrc, wf + 0 * 4096,
                                                   wf + 1 * 4096, b1, nullptr, hbf);
  k_layerf<false, false><<<1563, 256, 0, stream>>>(hbf, off, esrc, wf + 2 * 4096,
                                                   wf + 3 * 4096, b2, (float*)d_out, nullptr);
}